// Round 10
// baseline (397.426 us; speedup 1.0000x reference)
//
#include <hip/hip_runtime.h>

// AdderNet 2D: out[n,f,h,w] = -sum_{c,kh,kw} |W[f,c,kh,kw] - xpad[n,c,h+kh,w+kw]|
// x: (16,64,14,14) fp32, W: (64,64,3,3) fp32, out: (16,64,14,14) fp32
//
// R10 DIAGNOSTIC: R9 body (lane=f, W in 36 VGPRs const-indexed, x rows via
// wave-uniform ds_read_b128 broadcasts from a 3KB LDS tile) with the HOT
// LOOP repeated REPS=16x (accumulate, scale 1/16). A per-rep empty asm
// memory clobber forbids cross-rep CSE of the LDS reads; everything stays
// fully unrolled (no dynamic indexing -> no scratch demotion, R8 lesson).
// Decomposes kernel time = REPS*marginal(hot loop) + intercept(staging +
// reduce + atomics + launch) and surfaces the body's real counters.

#define N_ 16
#define C_ 64
#define F_ 64
#define P_ 196
#define REPS 16

__global__ __launch_bounds__(256, 4) void adder2d_kernel(
    const float* __restrict__ x, const float* __restrict__ w,
    float* __restrict__ out)
{
    // [c(16)][r(3)][col(16, zero-padded)] = 768 floats = 3 KB
    __shared__ __align__(16) float xs[16 * 48];
    __shared__ float part[4][64 * 15];   // stride 15 -> conflict-free

    const int tid = threadIdx.x;        // 0..255
    const int row = blockIdx.x;         // 0..13 output row
    const int n   = blockIdx.y;         // 0..15
    const int cs  = blockIdx.z;         // 0..3 channel slice (16 ch)
    const int f   = tid & 63;           // lane = filter
    const int wid = tid >> 6;           // wave 0..3 -> ch quad
    const int cbase = cs * 16 + wid * 4;

    // ---- stage 16ch x 3 rows x 16 cols (padded) into LDS: 3 stores/thr ----
    #pragma unroll
    for (int i = 0; i < 3; ++i) {
        const int idx = tid + 256 * i;          // 0..767
        const int c   = idx / 48;
        const int rem = idx - c * 48;
        const int r   = rem >> 4;               // 0..2
        const int col = rem & 15;               // 0..15
        const int ir  = row + r - 1;            // input row, -1..14
        float v = 0.f;
        if (col >= 1 && col <= 14 && ir >= 0 && ir <= 13)
            v = x[(n * C_ + cs * 16 + c) * P_ + ir * 14 + (col - 1)];
        xs[idx] = v;
    }

    // ---- W[f][cbase..cbase+3][0..8]: 36 floats, 9 dwordx4, loaded once ----
    float Wr[36];
    {
        const float4* wp = (const float4*)(w + f * (C_ * 9) + cbase * 9);
        #pragma unroll
        for (int i = 0; i < 9; ++i) {
            float4 t = wp[i];
            Wr[4 * i + 0] = t.x; Wr[4 * i + 1] = t.y;
            Wr[4 * i + 2] = t.z; Wr[4 * i + 3] = t.w;
        }
    }

    float acc[14];
    #pragma unroll
    for (int p = 0; p < 14; ++p) acc[p] = 0.f;

    __syncthreads();

    const float* xb = xs + (wid * 4) * 48;   // this wave's ch-quad base

    #pragma unroll 1
    for (int rep = 0; rep < REPS; ++rep) {
        asm volatile("" ::: "memory");   // forbid cross-rep LDS-read CSE
        #pragma unroll
        for (int cl = 0; cl < 4; ++cl) {
            #pragma unroll
            for (int kh = 0; kh < 3; ++kh) {
                const float4* rp = (const float4*)(xb + cl * 48 + kh * 16);
                float4 q0 = rp[0], q1 = rp[1], q2 = rp[2], q3 = rp[3];
                float xr[16] = {q0.x, q0.y, q0.z, q0.w,  q1.x, q1.y, q1.z, q1.w,
                                q2.x, q2.y, q2.z, q2.w,  q3.x, q3.y, q3.z, q3.w};
                #pragma unroll
                for (int kw = 0; kw < 3; ++kw) {
                    const float wv = Wr[cl * 9 + kh * 3 + kw];  // const index
                    #pragma unroll
                    for (int p = 0; p < 14; ++p)
                        acc[p] += fabsf(wv - xr[p + kw]);
                }
            }
        }
    }

    // ---- 4-wave partial reduce in LDS (scale out the reps) ----
    #pragma unroll
    for (int p = 0; p < 14; ++p)
        part[wid][f * 15 + p] = acc[p] * (1.0f / REPS);
    __syncthreads();

    // ---- 896 outputs this block; atomic add into zeroed d_out ----
    for (int o = tid; o < 896; o += 256) {
        const int ff = o / 14;
        const int px = o - ff * 14;
        const int a  = ff * 15 + px;
        float s = part[0][a] + part[1][a] + part[2][a] + part[3][a];
        atomicAdd(&out[(n * F_ + ff) * P_ + row * 14 + px], -s);
    }
}

extern "C" void kernel_launch(void* const* d_in, const int* in_sizes, int n_in,
                              void* d_out, int out_size, void* d_ws, size_t ws_size,
                              hipStream_t stream) {
    const float* x = (const float*)d_in[0];
    const float* w = (const float*)d_in[1];
    float* out = (float*)d_out;
    // d_out is re-poisoned 0xAA before every call -> zero it (graph-legal)
    hipMemsetAsync(out, 0, (size_t)out_size * sizeof(float), stream);
    dim3 grid(14, N_, 4);
    adder2d_kernel<<<grid, 256, 0, stream>>>(x, w, out);
}

// Round 11
// 69.432 us; speedup vs baseline: 5.7240x; 5.7240x over previous
//
#include <hip/hip_runtime.h>

// AdderNet 2D: out[n,f,h,w] = -sum_{c,kh,kw} |W[f,c,kh,kw] - xpad[n,c,h+kh,w+kw]|
// x: (16,64,14,14) fp32, W: (64,64,3,3) fp32, out: (16,64,14,14) fp32
//
// R11 = the no-defect combination, per R10's smoking gun (R10: launch_
// bounds(256,4) made the allocator target 64 VGPRs and spill ~95 dwords/
// thread -> 1.4 GB scratch HBM traffic = the entire 21us/pass cost).
//  - R9 body: lane = f, W in 36 VGPRs (const-indexed, fully unrolled),
//    x rows via wave-uniform ds_read_b128 broadcasts (no s_load chain,
//    conflict-free) from a 3 KB LDS tile.
//  - R3's register discipline: PLAIN __launch_bounds__(256) -> compiler
//    allocates what it needs (R3 measured VGPR=132, FETCH 3.3 MB, 0 spill).
//  - R7 grid: (14 row, 16 n, 4 cslice) = 896 blocks = 3.5/CU occupancy;
//    cross-block c-reduce via atomicAdd onto memset-zeroed d_out.

#define N_ 16
#define C_ 64
#define F_ 64
#define P_ 196

__global__ __launch_bounds__(256) void adder2d_kernel(
    const float* __restrict__ x, const float* __restrict__ w,
    float* __restrict__ out)
{
    // [c(16)][r(3)][col(16, zero-padded)] = 768 floats = 3 KB
    __shared__ __align__(16) float xs[16 * 48];
    __shared__ float part[4][64 * 15];   // stride 15 -> conflict-free

    const int tid = threadIdx.x;        // 0..255
    const int row = blockIdx.x;         // 0..13 output row
    const int n   = blockIdx.y;         // 0..15
    const int cs  = blockIdx.z;         // 0..3 channel slice (16 ch)
    const int f   = tid & 63;           // lane = filter
    const int wid = tid >> 6;           // wave 0..3 -> ch quad
    const int cbase = cs * 16 + wid * 4;

    // ---- stage 16ch x 3 rows x 16 cols (padded) into LDS: 3 stores/thr ----
    #pragma unroll
    for (int i = 0; i < 3; ++i) {
        const int idx = tid + 256 * i;          // 0..767
        const int c   = idx / 48;
        const int rem = idx - c * 48;
        const int r   = rem >> 4;               // 0..2
        const int col = rem & 15;               // 0..15
        const int ir  = row + r - 1;            // input row, -1..14
        float v = 0.f;
        if (col >= 1 && col <= 14 && ir >= 0 && ir <= 13)
            v = x[(n * C_ + cs * 16 + c) * P_ + ir * 14 + (col - 1)];
        xs[idx] = v;
    }

    // ---- W[f][cbase..cbase+3][0..8]: 36 floats, 9 dwordx4, loaded once ----
    float Wr[36];
    {
        const float4* wp = (const float4*)(w + f * (C_ * 9) + cbase * 9);
        #pragma unroll
        for (int i = 0; i < 9; ++i) {
            float4 t = wp[i];
            Wr[4 * i + 0] = t.x; Wr[4 * i + 1] = t.y;
            Wr[4 * i + 2] = t.z; Wr[4 * i + 3] = t.w;
        }
    }

    float acc[14];
    #pragma unroll
    for (int p = 0; p < 14; ++p) acc[p] = 0.f;

    __syncthreads();

    // ---- hot loop: 12 sections of (4 ds_read_b128 broadcast + 84 VALU) ----
    const float* xb = xs + (wid * 4) * 48;   // this wave's ch-quad base
    #pragma unroll
    for (int cl = 0; cl < 4; ++cl) {
        #pragma unroll
        for (int kh = 0; kh < 3; ++kh) {
            const float4* rp = (const float4*)(xb + cl * 48 + kh * 16);
            float4 q0 = rp[0], q1 = rp[1], q2 = rp[2], q3 = rp[3];
            float xr[16] = {q0.x, q0.y, q0.z, q0.w,  q1.x, q1.y, q1.z, q1.w,
                            q2.x, q2.y, q2.z, q2.w,  q3.x, q3.y, q3.z, q3.w};
            #pragma unroll
            for (int kw = 0; kw < 3; ++kw) {
                const float wv = Wr[cl * 9 + kh * 3 + kw];  // const index
                #pragma unroll
                for (int p = 0; p < 14; ++p)
                    acc[p] += fabsf(wv - xr[p + kw]);       // sub + add|.|
            }
        }
    }

    // ---- 4-wave partial reduce in LDS ----
    #pragma unroll
    for (int p = 0; p < 14; ++p) part[wid][f * 15 + p] = acc[p];
    __syncthreads();

    // ---- 896 outputs this block; atomic add into zeroed d_out ----
    for (int o = tid; o < 896; o += 256) {
        const int ff = o / 14;
        const int px = o - ff * 14;
        const int a  = ff * 15 + px;
        float s = part[0][a] + part[1][a] + part[2][a] + part[3][a];
        atomicAdd(&out[(n * F_ + ff) * P_ + row * 14 + px], -s);
    }
}

extern "C" void kernel_launch(void* const* d_in, const int* in_sizes, int n_in,
                              void* d_out, int out_size, void* d_ws, size_t ws_size,
                              hipStream_t stream) {
    const float* x = (const float*)d_in[0];
    const float* w = (const float*)d_in[1];
    float* out = (float*)d_out;
    // d_out is re-poisoned 0xAA before every call -> zero it (graph-legal)
    hipMemsetAsync(out, 0, (size_t)out_size * sizeof(float), stream);
    dim3 grid(14, N_, 4);
    adder2d_kernel<<<grid, 256, 0, stream>>>(x, w, out);
}